// Round 5
// baseline (530.281 us; speedup 1.0000x reference)
//
#include <hip/hip_runtime.h>
#include <math.h>

#define BATCH 128
#define S 50
#define D 128
#define SAMPLE 12

typedef __attribute__((ext_vector_type(8))) short short8v;
typedef __attribute__((ext_vector_type(4))) float f32x4;
typedef unsigned short u16;

__device__ __forceinline__ float leakyf(float x) { return x >= 0.f ? x : 0.2f * x; }
__device__ __forceinline__ u16 f2bf(float f) {
    union { float f; unsigned u; } v; v.f = f;
    unsigned u = v.u;
    return (u16)((u + 0x7FFFu + ((u >> 16) & 1u)) >> 16);  // RNE
}
__device__ __forceinline__ float bf2f(u16 h) {
    union { float f; unsigned u; } v; v.u = ((unsigned)h) << 16; return v.f;
}

// ---------------------------------------------------------------------------
// setup1: session + n1 (1-hop indices) + nw0 (1-hop weights)
// ---------------------------------------------------------------------------
__global__ __launch_bounds__(256) void setup1_kernel(
    const int* __restrict__ item, const int* __restrict__ mask,
    const int* __restrict__ inputs, const int* __restrict__ adj_all,
    const float* __restrict__ num_weight, const float* __restrict__ emb,
    float* __restrict__ session, int* __restrict__ n1, float* __restrict__ nw0)
{
    const int bx = blockIdx.x, t = threadIdx.x;
    if (bx < BATCH) {
        if (t < 128) {
            float num = 0.f, den = 0.f;
            for (int s = 0; s < S; ++s) {
                float m = (float)mask[bx * S + s];
                num += m * emb[item[bx * S + s] * D + t];
                den += m;
            }
            session[bx * D + t] = num / den;
        }
    } else {
        int idx = (bx - BATCH) * 256 + t;
        if (idx < BATCH * 600) {
            int b = idx / 600, j = idx % 600;
            int node = inputs[b * S + j / SAMPLE];
            n1[idx]  = adj_all[node * SAMPLE + j % SAMPLE];
            nw0[idx] = num_weight[node * SAMPLE + j % SAMPLE];
        }
    }
}

// ---------------------------------------------------------------------------
// prep2: emb->bf16, sessW1 bf16, W3T bf16, and PERMUTED gather tables:
//   n2p[b][lblk][i][c] / n1p[...]: byte offsets into emb_bf in staging order
//   nw1[b][7200]: 2-hop weights in true sample order
// ---------------------------------------------------------------------------
__global__ __launch_bounds__(256) void prep2_kernel(
    const float* __restrict__ emb, const float* __restrict__ w1,
    const float* __restrict__ w3, const float* __restrict__ session,
    const int* __restrict__ adj_all, const float* __restrict__ num_weight,
    const int* __restrict__ n1,
    u16* __restrict__ emb_bf, u16* __restrict__ sw1, u16* __restrict__ w3t,
    int* __restrict__ n2p, int* __restrict__ n1p, float* __restrict__ nw1)
{
    const int bx = blockIdx.x, t = threadIdx.x;
    if (bx < 2500) {                       // embedding -> bf16, 8 elems/thread
        int idx = bx * 256 + t;
        const float4* src = reinterpret_cast<const float4*>(emb) + (size_t)idx * 2;
        float4 a = src[0], c = src[1];
        u16 o[8] = {f2bf(a.x), f2bf(a.y), f2bf(a.z), f2bf(a.w),
                    f2bf(c.x), f2bf(c.y), f2bf(c.z), f2bf(c.w)};
        *reinterpret_cast<uint4*>(emb_bf + (size_t)idx * 8) = *reinterpret_cast<uint4*>(o);
    } else if (bx < 2756) {                // sessW1: block = (hop,b)
        int id = bx - 2500, hop = id >> 7, b = id & 127;
        const float* w1s = w1 + hop * 129 * 128;
        const float* se = session + b * 128;
        int n = t >> 1, kh = (t & 1) * 64;
        u16* dst = sw1 + (((size_t)(hop * 128 + b) * 128 + n) * 128) + kh;
        for (int kq = 0; kq < 64; kq += 8) {
            u16 o[8];
            #pragma unroll
            for (int e = 0; e < 8; ++e) { int k = kh + kq + e; o[e] = f2bf(w1s[k * 128 + n] * se[k]); }
            *reinterpret_cast<uint4*>(dst + kq) = *reinterpret_cast<uint4*>(o);
        }
    } else if (bx < 2788) {                // W3T [hop][n][k]
        int j = (bx - 2756) * 256 + t;     // < 8192
        int hop = j >> 12, r = j & 4095, n = r >> 5, k0 = (r & 31) * 8;
        const float* w3s = w3 + hop * 256 * 128;
        u16 o[8];
        #pragma unroll
        for (int e = 0; e < 8; ++e) o[e] = f2bf(w3s[(k0 + e) * 128 + n]);
        *reinterpret_cast<uint4*>(w3t + ((size_t)hop * 128 + n) * 256 + k0) = *reinterpret_cast<uint4*>(o);
    } else if (bx < 6388) {                // n2p (permuted byte-offsets) + nw1
        int idx = (bx - 2788) * 256 + t;
        if (idx < BATCH * 7200) {
            int b = idx / 7200, r = idx % 7200;
            int lblk = r / 96, q = r % 96;
            int i = q >> 4, c = q & 15;
            int gm = lblk * 96 + (c >> 2) * 24 + i * 4 + (c & 3);
            int node = n1[b * 600 + gm / SAMPLE];
            int s = gm % SAMPLE;
            n2p[idx] = adj_all[node * SAMPLE + s] << 8;
            nw1[b * 7200 + gm] = num_weight[node * SAMPLE + s];
        }
    } else {                               // n1p (mode0, permuted byte-offsets)
        int idx = (bx - 6388) * 256 + t;
        if (idx < BATCH * 672) {
            int b = idx / 672, r = idx % 672;
            int lblk = r / 96, q = r % 96;
            int i = q >> 4, c = q & 15;
            int gm = lblk * 96 + (c >> 2) * 24 + i * 4 + (c & 3);
            int jc = (gm < 600) ? gm : 0;
            n1p[idx] = n1[b * 600 + jc] << 8;
        }
    }
}

// ---------------------------------------------------------------------------
// Fused main kernel. 8 l-rows (96 samples) per block, 4 waves, 2 barriers.
// PATH 0, grid (83,128): bx==0 -> local_agg -> d_out; bx 1..7 -> mode0 -> out0;
//                        bx 8..82 -> mode1 -> out1.
// PATH 2, grid (7,128):  mode2 (self=out0, neigh=out1, hop1) += d_out.
// ---------------------------------------------------------------------------
template <int PATH>
__global__ __launch_bounds__(256, 5) void main_kernel(
    const int* __restrict__ inputs, const int* __restrict__ adj,
    const u16* __restrict__ emb_bf, const float* __restrict__ a_local,
    const int* __restrict__ n1, const int* __restrict__ n2p,
    const int* __restrict__ n1p,
    const float* __restrict__ nw0, const float* __restrict__ nw1,
    const u16* __restrict__ sw1, const float* __restrict__ w1,
    const float* __restrict__ w2, const u16* __restrict__ w3t,
    const u16* __restrict__ in0, const u16* __restrict__ in1,
    u16* __restrict__ o0, u16* __restrict__ o1, float* __restrict__ outf)
{
    __shared__ __align__(16) char smem[30592];
    const int b = blockIdx.y;
    const int t = threadIdx.x;
    const int bx = blockIdx.x;

    if (PATH == 0 && bx == 0) {
        // ------------------- local aggregation (conflict-free layout) -----
        u16*   ht    = (u16*)smem;              // [128][52] bf16 = 13312 B
        float* alpha = (float*)(smem + 13312);  // [50][51] f32  = 10200 B
        u16*   alb   = (u16*)(smem + 23520);    // [4][128] bf16 = 1024 B

        for (int idx = t; idx < S * D; idx += 256) {
            int i = idx >> 7, d = idx & 127;
            ht[d * 52 + i] = emb_bf[(size_t)inputs[b * S + i] * D + d];
        }
        for (int idx = t; idx < 512; idx += 256) alb[idx] = f2bf(a_local[idx]);
        __syncthreads();

        for (int p = t; p < S * S; p += 256) {
            int i = p / S, j = p % S;
            int a = adj[b * S * S + p];
            float v = -9e15f;
            if (a >= 1 && a <= 4) {
                const u16* ak = alb + (a - 1) * D;
                float dot = 0.f;
                #pragma unroll 4
                for (int d = 0; d < D; ++d)
                    dot += bf2f(ht[d * 52 + i]) * bf2f(ht[d * 52 + j]) * bf2f(ak[d]);
                v = leakyf(dot);
            }
            alpha[i * 51 + j] = v;
        }
        __syncthreads();

        if (t < S) {
            float m = -INFINITY;
            for (int j = 0; j < S; ++j) m = fmaxf(m, alpha[t * 51 + j]);
            float ssum = 0.f;
            for (int j = 0; j < S; ++j) { float e = __expf(alpha[t * 51 + j] - m); alpha[t * 51 + j] = e; ssum += e; }
            float inv = 1.f / ssum;
            for (int j = 0; j < S; ++j) alpha[t * 51 + j] *= inv;
        }
        __syncthreads();

        for (int idx = t; idx < S * D; idx += 256) {
            int i = idx >> 7, d = idx & 127;
            float acc = 0.f;
            #pragma unroll 5
            for (int j = 0; j < S; ++j) acc += alpha[i * 51 + j] * bf2f(ht[d * 52 + j]);
            outf[(size_t)b * S * D + idx] = acc;
        }
        return;
    }

    // ------------------- global aggregation -------------------
    int mode, lblk, L, Lm, hop;
    const u16 *nsrc, *ssrc;
    const int* ptab; const float* nwTab;
    u16* outb;
    if (PATH == 2)    { mode = 2; lblk = bx;     L = 50;  Lm = 600;  hop = 1; nsrc = in1;    ssrc = in0;    ptab = nullptr;                   nwTab = nw0; outb = nullptr; }
    else if (bx >= 8) { mode = 1; lblk = bx - 8; L = 600; Lm = 7200; hop = 0; nsrc = emb_bf; ssrc = emb_bf; ptab = n2p + (b * 75 + lblk) * 96; nwTab = nw1; outb = o1; }
    else              { mode = 0; lblk = bx - 1; L = 50;  Lm = 600;  hop = 0; nsrc = emb_bf; ssrc = emb_bf; ptab = n1p + (b * 7 + lblk) * 96;  nwTab = nw0; outb = o0; }
    const int l0 = lblk * 8;

    u16*   nvL     = (u16*)smem;              // 1536 slots * 16B = 24576
    u16*   selfL   = (u16*)(smem + 24576);    // 256 slots * 16B = 4096
    float* score_w = (float*)(smem + 28672);  // [96][4] = 1536
    float* nwgtL   = (float*)(smem + 30208);  // 96 floats = 384

    const u16*   sw1b   = sw1 + (size_t)(hop * 128 + b) * 16384;
    const float* w1last = w1 + hop * 129 * 128 + 128 * 128;
    const float* w2h    = w2 + hop * 128;
    const u16*   w3th   = w3t + hop * 32768;

    const int lane = t & 63, wv = t >> 6, cn = lane & 15, cg = lane >> 4;
    const int nc0 = (2 * wv) * 16 + cn, nc1 = (2 * wv + 1) * 16 + cn;
    const int c = t & 15;        // row selector within 16-row group
    const int chunk = t >> 4;    // 16B chunk 0..15 of a 256B row

    // ---- stage neighbor rows (fragment order, conflict-free) ----
    #pragma unroll
    for (int i = 0; i < 6; ++i) {
        int off;
        if (PATH == 2) {
            int gm = l0 * 12 + (c >> 2) * 24 + i * 4 + (c & 3);
            if (gm > 599) gm = 599;
            off = (b * 600 + gm) << 8;
        } else {
            off = ptab[i * 16 + c];   // 64B broadcast load
        }
        uint4 v = *reinterpret_cast<const uint4*>((const char*)nsrc + (unsigned)off + chunk * 16);
        *reinterpret_cast<uint4*>(nvL + (i * 256 + t) * 8) = v;
    }
    // ---- stage self rows: A row i2 holds l = 2*(i2>>2) + ((i2>>1)&1) ----
    {
        int l = 2 * (c >> 2) + ((c >> 1) & 1);
        int lg = l0 + l; if (lg >= L) lg = 0;
        int srow;
        if (PATH == 2)      srow = b * 50 + lg;
        else if (mode == 1) srow = n1[b * 600 + lg];
        else                srow = inputs[b * S + lg];
        uint4 v = *reinterpret_cast<const uint4*>(ssrc + (size_t)srow * 128 + chunk * 8);
        *reinterpret_cast<uint4*>(selfL + t * 8) = v;
    }
    if (t < 96) {
        int gm = l0 * 12 + t;
        nwgtL[t] = (gm < Lm) ? nwTab[b * Lm + gm] : 0.f;
    }
    __syncthreads();

    // ---- GEMM1: z[96,128] = nv @ sessW1 ----
    f32x4 acc[6][2];
    #pragma unroll
    for (int mt = 0; mt < 6; ++mt) {
        acc[mt][0] = (f32x4){0.f, 0.f, 0.f, 0.f};
        acc[mt][1] = (f32x4){0.f, 0.f, 0.f, 0.f};
    }
    #pragma unroll
    for (int kk = 0; kk < 4; ++kk) {
        int kb = kk * 32 + cg * 8;
        short8v b0 = *reinterpret_cast<const short8v*>(sw1b + nc0 * 128 + kb);
        short8v b1 = *reinterpret_cast<const short8v*>(sw1b + nc1 * 128 + kb);
        #pragma unroll
        for (int mt = 0; mt < 6; ++mt) {
            short8v a = *reinterpret_cast<const short8v*>(nvL + ((mt * 4 + kk) * 64 + lane) * 8);
            acc[mt][0] = __builtin_amdgcn_mfma_f32_16x16x32_bf16(a, b0, acc[mt][0], 0, 0, 0);
            acc[mt][1] = __builtin_amdgcn_mfma_f32_16x16x32_bf16(a, b1, acc[mt][1], 0, 0, 0);
        }
    }
    // ---- score epilogue: K=129 rank-1 + leaky + @W2, reduce over 16 lanes ----
    {
        float w2v0 = w2h[nc0], w2v1 = w2h[nc1];
        float w1l0 = w1last[nc0], w1l1 = w1last[nc1];
        #pragma unroll
        for (int mt = 0; mt < 6; ++mt) {
            #pragma unroll
            for (int r = 0; r < 4; ++r) {
                int m = cg * 24 + mt * 4 + r;
                float nw = nwgtL[m];
                float v = leakyf(acc[mt][0][r] + nw * w1l0) * w2v0 +
                          leakyf(acc[mt][1][r] + nw * w1l1) * w2v1;
                v += __shfl_xor(v, 1); v += __shfl_xor(v, 2);
                v += __shfl_xor(v, 4); v += __shfl_xor(v, 8);
                if (cn == 0) score_w[m * 4 + wv] = v;
            }
        }
    }
    __syncthreads();

    // ---- per-lane redundant softmax over 12 samples for l=2cg, 2cg+1 ----
    float alph[24];
    {
        const f32x4* sw4 = reinterpret_cast<const f32x4*>(score_w);
        float mx0 = -1e30f, mx1 = -1e30f;
        #pragma unroll
        for (int q = 0; q < 24; ++q) {
            f32x4 s4 = sw4[cg * 24 + q];
            float s = (s4[0] + s4[1]) + (s4[2] + s4[3]);
            alph[q] = s;
            if (q < 12) mx0 = fmaxf(mx0, s); else mx1 = fmaxf(mx1, s);
        }
        float sm0 = 0.f, sm1 = 0.f;
        #pragma unroll
        for (int q = 0; q < 12; ++q) { alph[q] = __expf(alph[q] - mx0); sm0 += alph[q]; }
        #pragma unroll
        for (int q = 12; q < 24; ++q) { alph[q] = __expf(alph[q] - mx1); sm1 += alph[q]; }
        float i0 = 1.f / sm0, i1 = 1.f / sm1;
        #pragma unroll
        for (int q = 0; q < 12; ++q) alph[q] *= i0;
        #pragma unroll
        for (int q = 12; q < 24; ++q) alph[q] *= i1;
    }

    // ---- GEMM2 per output col: Y = nv @ W3b, Ys = self @ W3a; combine ----
    #pragma unroll
    for (int j = 0; j < 2; ++j) {
        int nc = (2 * wv + j) * 16 + cn;
        f32x4 Y[6]; f32x4 Ys = (f32x4){0.f, 0.f, 0.f, 0.f};
        #pragma unroll
        for (int mt = 0; mt < 6; ++mt) Y[mt] = (f32x4){0.f, 0.f, 0.f, 0.f};
        #pragma unroll
        for (int kk = 0; kk < 4; ++kk) {
            int kb = kk * 32 + cg * 8;
            short8v bw = *reinterpret_cast<const short8v*>(w3th + nc * 256 + 128 + kb);
            short8v bs = *reinterpret_cast<const short8v*>(w3th + nc * 256 + kb);
            short8v aS = *reinterpret_cast<const short8v*>(selfL + (kk * 64 + lane) * 8);
            Ys = __builtin_amdgcn_mfma_f32_16x16x32_bf16(aS, bs, Ys, 0, 0, 0);
            #pragma unroll
            for (int mt = 0; mt < 6; ++mt) {
                short8v a = *reinterpret_cast<const short8v*>(nvL + ((mt * 4 + kk) * 64 + lane) * 8);
                Y[mt] = __builtin_amdgcn_mfma_f32_16x16x32_bf16(a, bw, Y[mt], 0, 0, 0);
            }
        }
        float P0 = 0.f, P1 = 0.f;
        #pragma unroll
        for (int q = 0; q < 12; ++q) P0 += alph[q] * Y[q >> 2][q & 3];
        #pragma unroll
        for (int q = 12; q < 24; ++q) P1 += alph[q] * Y[q >> 2][q & 3];
        float v0 = fmaxf(P0 + Ys[0], 0.f);   // l = 2cg
        float v1 = fmaxf(P1 + Ys[2], 0.f);   // l = 2cg+1
        int lg0 = l0 + cg * 2, lg1 = lg0 + 1;
        if (PATH == 2) {
            if (lg0 < L) { float* p = outf + ((size_t)b * 50 + lg0) * 128 + nc; *p += v0; }
            if (lg1 < L) { float* p = outf + ((size_t)b * 50 + lg1) * 128 + nc; *p += v1; }
        } else {
            if (lg0 < L) outb[((size_t)b * L + lg0) * 128 + nc] = f2bf(v0);
            if (lg1 < L) outb[((size_t)b * L + lg1) * 128 + nc] = f2bf(v1);
        }
    }
}

// ---------------------------------------------------------------------------
extern "C" void kernel_launch(void* const* d_in, const int* in_sizes, int n_in,
                              void* d_out, int out_size, void* d_ws, size_t ws_size,
                              hipStream_t stream)
{
    const int*   inputs     = (const int*)d_in[0];
    const int*   adj        = (const int*)d_in[1];
    const int*   mask_item  = (const int*)d_in[2];
    const int*   item       = (const int*)d_in[3];
    const int*   adj_all    = (const int*)d_in[4];
    const float* num_weight = (const float*)d_in[5];
    const float* embedding  = (const float*)d_in[6];
    const float* a_local    = (const float*)d_in[7];
    const float* agg_w1     = (const float*)d_in[8];
    const float* agg_w2     = (const float*)d_in[9];
    const float* agg_w3     = (const float*)d_in[10];
    float* out = (float*)d_out;

    // workspace layout (16B aligned)
    char* w = (char*)d_ws;
    float* ws_session = (float*)(w);               //     65,536 B
    int*   ws_n1      = (int*)(w + 65536);         //    307,200 B
    float* ws_nw0     = (float*)(w + 372736);      //    307,200 B
    float* ws_nw1     = (float*)(w + 679936);      //  3,686,400 B
    int*   ws_n2p     = (int*)(w + 4366336);       //  3,686,400 B
    int*   ws_n1p     = (int*)(w + 8052736);       //    344,064 B
    u16*   ws_emb     = (u16*)(w + 8396800);       // 10,240,000 B
    u16*   ws_sw1     = (u16*)(w + 18636800);      //  8,388,608 B
    u16*   ws_w3t     = (u16*)(w + 27025408);      //    131,072 B
    u16*   ws_out0    = (u16*)(w + 27156480);      //  1,638,400 B
    u16*   ws_out1    = (u16*)(w + 28794880);      // 19,660,800 B (end ~46.2 MB)

    setup1_kernel<<<dim3(BATCH + 300), 256, 0, stream>>>(
        item, mask_item, inputs, adj_all, num_weight, embedding,
        ws_session, ws_n1, ws_nw0);
    prep2_kernel<<<dim3(6724), 256, 0, stream>>>(
        embedding, agg_w1, agg_w3, ws_session, adj_all, num_weight, ws_n1,
        ws_emb, ws_sw1, ws_w3t, ws_n2p, ws_n1p, ws_nw1);

    // fused: local (bx=0) + mode0 (bx 1..7) + mode1 (bx 8..82) per batch
    main_kernel<0><<<dim3(83, BATCH), 256, 0, stream>>>(
        inputs, adj, ws_emb, a_local, ws_n1, ws_n2p, ws_n1p, ws_nw0, ws_nw1,
        ws_sw1, agg_w1, agg_w2, ws_w3t,
        nullptr, nullptr, ws_out0, ws_out1, out);

    // mode2: hop-1 weights, self=out0, neigh=out1, += h_local in d_out
    main_kernel<2><<<dim3(7, BATCH), 256, 0, stream>>>(
        inputs, adj, ws_emb, a_local, ws_n1, ws_n2p, ws_n1p, ws_nw0, ws_nw1,
        ws_sw1, agg_w1, agg_w2, ws_w3t,
        ws_out0, ws_out1, nullptr, nullptr, out);
}

// Round 6
// 457.046 us; speedup vs baseline: 1.1602x; 1.1602x over previous
//
#include <hip/hip_runtime.h>
#include <math.h>

#define BATCH 128
#define S 50
#define D 128
#define SAMPLE 12

typedef __attribute__((ext_vector_type(8))) short short8v;
typedef __attribute__((ext_vector_type(4))) float f32x4;
typedef unsigned short u16;

__device__ __forceinline__ float leakyf(float x) { return x >= 0.f ? x : 0.2f * x; }
__device__ __forceinline__ u16 f2bf(float f) {
    union { float f; unsigned u; } v; v.f = f;
    unsigned u = v.u;
    return (u16)((u + 0x7FFFu + ((u >> 16) & 1u)) >> 16);  // RNE
}
__device__ __forceinline__ float bf2f(u16 h) {
    union { float f; unsigned u; } v; v.u = ((unsigned)h) << 16; return v.f;
}

// ---------------------------------------------------------------------------
// setup1: session + n1 (1-hop indices) + nw0 (1-hop weights)
// ---------------------------------------------------------------------------
__global__ __launch_bounds__(256) void setup1_kernel(
    const int* __restrict__ item, const int* __restrict__ mask,
    const int* __restrict__ inputs, const int* __restrict__ adj_all,
    const float* __restrict__ num_weight, const float* __restrict__ emb,
    float* __restrict__ session, int* __restrict__ n1, float* __restrict__ nw0)
{
    const int bx = blockIdx.x, t = threadIdx.x;
    if (bx < BATCH) {
        if (t < 128) {
            float num = 0.f, den = 0.f;
            for (int s = 0; s < S; ++s) {
                float m = (float)mask[bx * S + s];
                num += m * emb[item[bx * S + s] * D + t];
                den += m;
            }
            session[bx * D + t] = num / den;
        }
    } else {
        int idx = (bx - BATCH) * 256 + t;
        if (idx < BATCH * 600) {
            int b = idx / 600, j = idx % 600;
            int node = inputs[b * S + j / SAMPLE];
            n1[idx]  = adj_all[node * SAMPLE + j % SAMPLE];
            nw0[idx] = num_weight[node * SAMPLE + j % SAMPLE];
        }
    }
}

// ---------------------------------------------------------------------------
// prep2: emb->bf16, sessW1 bf16, W3T bf16, and PERMUTED gather tables:
//   n2p[b][lblk][i][c] / n1p[...]: byte offsets into emb_bf in staging order
//   nw1[b][7200]: 2-hop weights in true sample order
// ---------------------------------------------------------------------------
__global__ __launch_bounds__(256) void prep2_kernel(
    const float* __restrict__ emb, const float* __restrict__ w1,
    const float* __restrict__ w3, const float* __restrict__ session,
    const int* __restrict__ adj_all, const float* __restrict__ num_weight,
    const int* __restrict__ n1,
    u16* __restrict__ emb_bf, u16* __restrict__ sw1, u16* __restrict__ w3t,
    int* __restrict__ n2p, int* __restrict__ n1p, float* __restrict__ nw1)
{
    const int bx = blockIdx.x, t = threadIdx.x;
    if (bx < 2500) {                       // embedding -> bf16, 8 elems/thread
        int idx = bx * 256 + t;
        const float4* src = reinterpret_cast<const float4*>(emb) + (size_t)idx * 2;
        float4 a = src[0], c = src[1];
        u16 o[8] = {f2bf(a.x), f2bf(a.y), f2bf(a.z), f2bf(a.w),
                    f2bf(c.x), f2bf(c.y), f2bf(c.z), f2bf(c.w)};
        *reinterpret_cast<uint4*>(emb_bf + (size_t)idx * 8) = *reinterpret_cast<uint4*>(o);
    } else if (bx < 2756) {                // sessW1: block = (hop,b)
        int id = bx - 2500, hop = id >> 7, b = id & 127;
        const float* w1s = w1 + hop * 129 * 128;
        const float* se = session + b * 128;
        int n = t >> 1, kh = (t & 1) * 64;
        u16* dst = sw1 + (((size_t)(hop * 128 + b) * 128 + n) * 128) + kh;
        for (int kq = 0; kq < 64; kq += 8) {
            u16 o[8];
            #pragma unroll
            for (int e = 0; e < 8; ++e) { int k = kh + kq + e; o[e] = f2bf(w1s[k * 128 + n] * se[k]); }
            *reinterpret_cast<uint4*>(dst + kq) = *reinterpret_cast<uint4*>(o);
        }
    } else if (bx < 2788) {                // W3T [hop][n][k]
        int j = (bx - 2756) * 256 + t;     // < 8192
        int hop = j >> 12, r = j & 4095, n = r >> 5, k0 = (r & 31) * 8;
        const float* w3s = w3 + hop * 256 * 128;
        u16 o[8];
        #pragma unroll
        for (int e = 0; e < 8; ++e) o[e] = f2bf(w3s[(k0 + e) * 128 + n]);
        *reinterpret_cast<uint4*>(w3t + ((size_t)hop * 128 + n) * 256 + k0) = *reinterpret_cast<uint4*>(o);
    } else if (bx < 6388) {                // n2p (permuted byte-offsets) + nw1
        int idx = (bx - 2788) * 256 + t;
        if (idx < BATCH * 7200) {
            int b = idx / 7200, r = idx % 7200;
            int lblk = r / 96, q = r % 96;
            int i = q >> 4, c = q & 15;
            int gm = lblk * 96 + (c >> 2) * 24 + i * 4 + (c & 3);
            int node = n1[b * 600 + gm / SAMPLE];
            int s = gm % SAMPLE;
            n2p[idx] = adj_all[node * SAMPLE + s] << 8;
            nw1[b * 7200 + gm] = num_weight[node * SAMPLE + s];
        }
    } else {                               // n1p (mode0, permuted byte-offsets)
        int idx = (bx - 6388) * 256 + t;
        if (idx < BATCH * 672) {
            int b = idx / 672, r = idx % 672;
            int lblk = r / 96, q = r % 96;
            int i = q >> 4, c = q & 15;
            int gm = lblk * 96 + (c >> 2) * 24 + i * 4 + (c & 3);
            int jc = (gm < 600) ? gm : 0;
            n1p[idx] = n1[b * 600 + jc] << 8;
        }
    }
}

// ---------------------------------------------------------------------------
// Fused main kernel. 8 l-rows (96 samples) per block, 4 waves, 2 barriers.
// PATH 0, grid (83,128): bx==0 -> local_agg -> d_out; bx 1..7 -> mode0 -> out0;
//                        bx 8..82 -> mode1 -> out1.
// PATH 2, grid (7,128):  mode2 (self=out0, neigh=out1, hop1) += d_out.
// NOTE: min-waves/EU MUST stay 4 — at 5 the allocator caps at <96 VGPR and
// spills alph[24]/Y[6] to scratch (round-5 regression: 986 MB scratch writes).
// ---------------------------------------------------------------------------
template <int PATH>
__global__ __launch_bounds__(256, 4) void main_kernel(
    const int* __restrict__ inputs, const int* __restrict__ adj,
    const u16* __restrict__ emb_bf, const float* __restrict__ a_local,
    const int* __restrict__ n1, const int* __restrict__ n2p,
    const int* __restrict__ n1p,
    const float* __restrict__ nw0, const float* __restrict__ nw1,
    const u16* __restrict__ sw1, const float* __restrict__ w1,
    const float* __restrict__ w2, const u16* __restrict__ w3t,
    const u16* __restrict__ in0, const u16* __restrict__ in1,
    u16* __restrict__ o0, u16* __restrict__ o1, float* __restrict__ outf)
{
    __shared__ __align__(16) char smem[30592];
    const int b = blockIdx.y;
    const int t = threadIdx.x;
    const int bx = blockIdx.x;

    if (PATH == 0 && bx == 0) {
        // ------------------- local aggregation (conflict-free layout) -----
        u16*   ht    = (u16*)smem;              // [128][52] bf16 = 13312 B
        float* alpha = (float*)(smem + 13312);  // [50][51] f32  = 10200 B
        u16*   alb   = (u16*)(smem + 23520);    // [4][128] bf16 = 1024 B

        for (int idx = t; idx < S * D; idx += 256) {
            int i = idx >> 7, d = idx & 127;
            ht[d * 52 + i] = emb_bf[(size_t)inputs[b * S + i] * D + d];
        }
        for (int idx = t; idx < 512; idx += 256) alb[idx] = f2bf(a_local[idx]);
        __syncthreads();

        for (int p = t; p < S * S; p += 256) {
            int i = p / S, j = p % S;
            int a = adj[b * S * S + p];
            float v = -9e15f;
            if (a >= 1 && a <= 4) {
                const u16* ak = alb + (a - 1) * D;
                float dot = 0.f;
                #pragma unroll 4
                for (int d = 0; d < D; ++d)
                    dot += bf2f(ht[d * 52 + i]) * bf2f(ht[d * 52 + j]) * bf2f(ak[d]);
                v = leakyf(dot);
            }
            alpha[i * 51 + j] = v;
        }
        __syncthreads();

        if (t < S) {
            float m = -INFINITY;
            for (int j = 0; j < S; ++j) m = fmaxf(m, alpha[t * 51 + j]);
            float ssum = 0.f;
            for (int j = 0; j < S; ++j) { float e = __expf(alpha[t * 51 + j] - m); alpha[t * 51 + j] = e; ssum += e; }
            float inv = 1.f / ssum;
            for (int j = 0; j < S; ++j) alpha[t * 51 + j] *= inv;
        }
        __syncthreads();

        for (int idx = t; idx < S * D; idx += 256) {
            int i = idx >> 7, d = idx & 127;
            float acc = 0.f;
            #pragma unroll 5
            for (int j = 0; j < S; ++j) acc += alpha[i * 51 + j] * bf2f(ht[d * 52 + j]);
            outf[(size_t)b * S * D + idx] = acc;
        }
        return;
    }

    // ------------------- global aggregation -------------------
    int mode, lblk, L, Lm, hop;
    const u16 *nsrc, *ssrc;
    const int* ptab; const float* nwTab;
    u16* outb;
    if (PATH == 2)    { mode = 2; lblk = bx;     L = 50;  Lm = 600;  hop = 1; nsrc = in1;    ssrc = in0;    ptab = nullptr;                   nwTab = nw0; outb = nullptr; }
    else if (bx >= 8) { mode = 1; lblk = bx - 8; L = 600; Lm = 7200; hop = 0; nsrc = emb_bf; ssrc = emb_bf; ptab = n2p + (b * 75 + lblk) * 96; nwTab = nw1; outb = o1; }
    else              { mode = 0; lblk = bx - 1; L = 50;  Lm = 600;  hop = 0; nsrc = emb_bf; ssrc = emb_bf; ptab = n1p + (b * 7 + lblk) * 96;  nwTab = nw0; outb = o0; }
    const int l0 = lblk * 8;

    u16*   nvL     = (u16*)smem;              // 1536 slots * 16B = 24576
    u16*   selfL   = (u16*)(smem + 24576);    // 256 slots * 16B = 4096
    float* score_w = (float*)(smem + 28672);  // [96][4] = 1536
    float* nwgtL   = (float*)(smem + 30208);  // 96 floats = 384

    const u16*   sw1b   = sw1 + (size_t)(hop * 128 + b) * 16384;
    const float* w1last = w1 + hop * 129 * 128 + 128 * 128;
    const float* w2h    = w2 + hop * 128;
    const u16*   w3th   = w3t + hop * 32768;

    const int lane = t & 63, wv = t >> 6, cn = lane & 15, cg = lane >> 4;
    const int nc0 = (2 * wv) * 16 + cn, nc1 = (2 * wv + 1) * 16 + cn;
    const int c = t & 15;        // row selector within 16-row group
    const int chunk = t >> 4;    // 16B chunk 0..15 of a 256B row

    // ---- stage neighbor rows (fragment order, conflict-free) ----
    #pragma unroll
    for (int i = 0; i < 6; ++i) {
        int off;
        if (PATH == 2) {
            int gm = l0 * 12 + (c >> 2) * 24 + i * 4 + (c & 3);
            if (gm > 599) gm = 599;
            off = (b * 600 + gm) << 8;
        } else {
            off = ptab[i * 16 + c];   // 64B broadcast load
        }
        uint4 v = *reinterpret_cast<const uint4*>((const char*)nsrc + (unsigned)off + chunk * 16);
        *reinterpret_cast<uint4*>(nvL + (i * 256 + t) * 8) = v;
    }
    // ---- stage self rows: A row i2 holds l = 2*(i2>>2) + ((i2>>1)&1) ----
    {
        int l = 2 * (c >> 2) + ((c >> 1) & 1);
        int lg = l0 + l; if (lg >= L) lg = 0;
        int srow;
        if (PATH == 2)      srow = b * 50 + lg;
        else if (mode == 1) srow = n1[b * 600 + lg];
        else                srow = inputs[b * S + lg];
        uint4 v = *reinterpret_cast<const uint4*>(ssrc + (size_t)srow * 128 + chunk * 8);
        *reinterpret_cast<uint4*>(selfL + t * 8) = v;
    }
    if (t < 96) {
        int gm = l0 * 12 + t;
        nwgtL[t] = (gm < Lm) ? nwTab[b * Lm + gm] : 0.f;
    }
    __syncthreads();

    // ---- GEMM1: z[96,128] = nv @ sessW1 ----
    f32x4 acc[6][2];
    #pragma unroll
    for (int mt = 0; mt < 6; ++mt) {
        acc[mt][0] = (f32x4){0.f, 0.f, 0.f, 0.f};
        acc[mt][1] = (f32x4){0.f, 0.f, 0.f, 0.f};
    }
    #pragma unroll
    for (int kk = 0; kk < 4; ++kk) {
        int kb = kk * 32 + cg * 8;
        short8v b0 = *reinterpret_cast<const short8v*>(sw1b + nc0 * 128 + kb);
        short8v b1 = *reinterpret_cast<const short8v*>(sw1b + nc1 * 128 + kb);
        #pragma unroll
        for (int mt = 0; mt < 6; ++mt) {
            short8v a = *reinterpret_cast<const short8v*>(nvL + ((mt * 4 + kk) * 64 + lane) * 8);
            acc[mt][0] = __builtin_amdgcn_mfma_f32_16x16x32_bf16(a, b0, acc[mt][0], 0, 0, 0);
            acc[mt][1] = __builtin_amdgcn_mfma_f32_16x16x32_bf16(a, b1, acc[mt][1], 0, 0, 0);
        }
    }
    // ---- score epilogue: K=129 rank-1 + leaky + @W2, reduce over 16 lanes ----
    {
        float w2v0 = w2h[nc0], w2v1 = w2h[nc1];
        float w1l0 = w1last[nc0], w1l1 = w1last[nc1];
        #pragma unroll
        for (int mt = 0; mt < 6; ++mt) {
            #pragma unroll
            for (int r = 0; r < 4; ++r) {
                int m = cg * 24 + mt * 4 + r;
                float nw = nwgtL[m];
                float v = leakyf(acc[mt][0][r] + nw * w1l0) * w2v0 +
                          leakyf(acc[mt][1][r] + nw * w1l1) * w2v1;
                v += __shfl_xor(v, 1); v += __shfl_xor(v, 2);
                v += __shfl_xor(v, 4); v += __shfl_xor(v, 8);
                if (cn == 0) score_w[m * 4 + wv] = v;
            }
        }
    }
    __syncthreads();

    // ---- per-lane redundant softmax over 12 samples for l=2cg, 2cg+1 ----
    float alph[24];
    {
        const f32x4* sw4 = reinterpret_cast<const f32x4*>(score_w);
        float mx0 = -1e30f, mx1 = -1e30f;
        #pragma unroll
        for (int q = 0; q < 24; ++q) {
            f32x4 s4 = sw4[cg * 24 + q];
            float s = (s4[0] + s4[1]) + (s4[2] + s4[3]);
            alph[q] = s;
            if (q < 12) mx0 = fmaxf(mx0, s); else mx1 = fmaxf(mx1, s);
        }
        float sm0 = 0.f, sm1 = 0.f;
        #pragma unroll
        for (int q = 0; q < 12; ++q) { alph[q] = __expf(alph[q] - mx0); sm0 += alph[q]; }
        #pragma unroll
        for (int q = 12; q < 24; ++q) { alph[q] = __expf(alph[q] - mx1); sm1 += alph[q]; }
        float i0 = 1.f / sm0, i1 = 1.f / sm1;
        #pragma unroll
        for (int q = 0; q < 12; ++q) alph[q] *= i0;
        #pragma unroll
        for (int q = 12; q < 24; ++q) alph[q] *= i1;
    }

    // ---- GEMM2 per output col: Y = nv @ W3b, Ys = self @ W3a; combine ----
    #pragma unroll
    for (int j = 0; j < 2; ++j) {
        int nc = (2 * wv + j) * 16 + cn;
        f32x4 Y[6]; f32x4 Ys = (f32x4){0.f, 0.f, 0.f, 0.f};
        #pragma unroll
        for (int mt = 0; mt < 6; ++mt) Y[mt] = (f32x4){0.f, 0.f, 0.f, 0.f};
        #pragma unroll
        for (int kk = 0; kk < 4; ++kk) {
            int kb = kk * 32 + cg * 8;
            short8v bw = *reinterpret_cast<const short8v*>(w3th + nc * 256 + 128 + kb);
            short8v bs = *reinterpret_cast<const short8v*>(w3th + nc * 256 + kb);
            short8v aS = *reinterpret_cast<const short8v*>(selfL + (kk * 64 + lane) * 8);
            Ys = __builtin_amdgcn_mfma_f32_16x16x32_bf16(aS, bs, Ys, 0, 0, 0);
            #pragma unroll
            for (int mt = 0; mt < 6; ++mt) {
                short8v a = *reinterpret_cast<const short8v*>(nvL + ((mt * 4 + kk) * 64 + lane) * 8);
                Y[mt] = __builtin_amdgcn_mfma_f32_16x16x32_bf16(a, bw, Y[mt], 0, 0, 0);
            }
        }
        float P0 = 0.f, P1 = 0.f;
        #pragma unroll
        for (int q = 0; q < 12; ++q) P0 += alph[q] * Y[q >> 2][q & 3];
        #pragma unroll
        for (int q = 12; q < 24; ++q) P1 += alph[q] * Y[q >> 2][q & 3];
        float v0 = fmaxf(P0 + Ys[0], 0.f);   // l = 2cg
        float v1 = fmaxf(P1 + Ys[2], 0.f);   // l = 2cg+1
        int lg0 = l0 + cg * 2, lg1 = lg0 + 1;
        if (PATH == 2) {
            if (lg0 < L) { float* p = outf + ((size_t)b * 50 + lg0) * 128 + nc; *p += v0; }
            if (lg1 < L) { float* p = outf + ((size_t)b * 50 + lg1) * 128 + nc; *p += v1; }
        } else {
            if (lg0 < L) outb[((size_t)b * L + lg0) * 128 + nc] = f2bf(v0);
            if (lg1 < L) outb[((size_t)b * L + lg1) * 128 + nc] = f2bf(v1);
        }
    }
}

// ---------------------------------------------------------------------------
extern "C" void kernel_launch(void* const* d_in, const int* in_sizes, int n_in,
                              void* d_out, int out_size, void* d_ws, size_t ws_size,
                              hipStream_t stream)
{
    const int*   inputs     = (const int*)d_in[0];
    const int*   adj        = (const int*)d_in[1];
    const int*   mask_item  = (const int*)d_in[2];
    const int*   item       = (const int*)d_in[3];
    const int*   adj_all    = (const int*)d_in[4];
    const float* num_weight = (const float*)d_in[5];
    const float* embedding  = (const float*)d_in[6];
    const float* a_local    = (const float*)d_in[7];
    const float* agg_w1     = (const float*)d_in[8];
    const float* agg_w2     = (const float*)d_in[9];
    const float* agg_w3     = (const float*)d_in[10];
    float* out = (float*)d_out;

    // workspace layout (16B aligned)
    char* w = (char*)d_ws;
    float* ws_session = (float*)(w);               //     65,536 B
    int*   ws_n1      = (int*)(w + 65536);         //    307,200 B
    float* ws_nw0     = (float*)(w + 372736);      //    307,200 B
    float* ws_nw1     = (float*)(w + 679936);      //  3,686,400 B
    int*   ws_n2p     = (int*)(w + 4366336);       //  3,686,400 B
    int*   ws_n1p     = (int*)(w + 8052736);       //    344,064 B
    u16*   ws_emb     = (u16*)(w + 8396800);       // 10,240,000 B
    u16*   ws_sw1     = (u16*)(w + 18636800);      //  8,388,608 B
    u16*   ws_w3t     = (u16*)(w + 27025408);      //    131,072 B
    u16*   ws_out0    = (u16*)(w + 27156480);      //  1,638,400 B
    u16*   ws_out1    = (u16*)(w + 28794880);      // 19,660,800 B (end ~46.2 MB)

    setup1_kernel<<<dim3(BATCH + 300), 256, 0, stream>>>(
        item, mask_item, inputs, adj_all, num_weight, embedding,
        ws_session, ws_n1, ws_nw0);
    prep2_kernel<<<dim3(6724), 256, 0, stream>>>(
        embedding, agg_w1, agg_w3, ws_session, adj_all, num_weight, ws_n1,
        ws_emb, ws_sw1, ws_w3t, ws_n2p, ws_n1p, ws_nw1);

    // fused: local (bx=0) + mode0 (bx 1..7) + mode1 (bx 8..82) per batch
    main_kernel<0><<<dim3(83, BATCH), 256, 0, stream>>>(
        inputs, adj, ws_emb, a_local, ws_n1, ws_n2p, ws_n1p, ws_nw0, ws_nw1,
        ws_sw1, agg_w1, agg_w2, ws_w3t,
        nullptr, nullptr, ws_out0, ws_out1, out);

    // mode2: hop-1 weights, self=out0, neigh=out1, += h_local in d_out
    main_kernel<2><<<dim3(7, BATCH), 256, 0, stream>>>(
        inputs, adj, ws_emb, a_local, ws_n1, ws_n2p, ws_n1p, ws_nw0, ws_nw1,
        ws_sw1, agg_w1, agg_w2, ws_w3t,
        ws_out0, ws_out1, nullptr, nullptr, out);
}

// Round 7
// 348.563 us; speedup vs baseline: 1.5213x; 1.3112x over previous
//
#include <hip/hip_runtime.h>
#include <math.h>

#define BATCH 128
#define S 50
#define D 128
#define SAMPLE 12

typedef __attribute__((ext_vector_type(8))) short short8v;
typedef __attribute__((ext_vector_type(4))) float f32x4;
typedef unsigned short u16;

__device__ __forceinline__ float leakyf(float x) { return x >= 0.f ? x : 0.2f * x; }
__device__ __forceinline__ u16 f2bf(float f) {
    union { float f; unsigned u; } v; v.f = f;
    unsigned u = v.u;
    return (u16)((u + 0x7FFFu + ((u >> 16) & 1u)) >> 16);  // RNE
}
__device__ __forceinline__ float bf2f(u16 h) {
    union { float f; unsigned u; } v; v.u = ((unsigned)h) << 16; return v.f;
}

// ---------------------------------------------------------------------------
// setup1: session + n1 (1-hop indices) + nw0 (1-hop weights)
// ---------------------------------------------------------------------------
__global__ __launch_bounds__(256) void setup1_kernel(
    const int* __restrict__ item, const int* __restrict__ mask,
    const int* __restrict__ inputs, const int* __restrict__ adj_all,
    const float* __restrict__ num_weight, const float* __restrict__ emb,
    float* __restrict__ session, int* __restrict__ n1, float* __restrict__ nw0)
{
    const int bx = blockIdx.x, t = threadIdx.x;
    if (bx < BATCH) {
        if (t < 128) {
            float num = 0.f, den = 0.f;
            for (int s = 0; s < S; ++s) {
                float m = (float)mask[bx * S + s];
                num += m * emb[item[bx * S + s] * D + t];
                den += m;
            }
            session[bx * D + t] = num / den;
        }
    } else {
        int idx = (bx - BATCH) * 256 + t;
        if (idx < BATCH * 600) {
            int b = idx / 600, j = idx % 600;
            int node = inputs[b * S + j / SAMPLE];
            n1[idx]  = adj_all[node * SAMPLE + j % SAMPLE];
            nw0[idx] = num_weight[node * SAMPLE + j % SAMPLE];
        }
    }
}

// ---------------------------------------------------------------------------
// prep2: emb->bf16, sessW1 bf16, W3T bf16, and PERMUTED gather tables:
//   n2p[b][lblk][i][c] / n1p[...]: byte offsets into emb_bf in staging order
//   nw1[b][7200]: 2-hop weights in true sample order
// ---------------------------------------------------------------------------
__global__ __launch_bounds__(256) void prep2_kernel(
    const float* __restrict__ emb, const float* __restrict__ w1,
    const float* __restrict__ w3, const float* __restrict__ session,
    const int* __restrict__ adj_all, const float* __restrict__ num_weight,
    const int* __restrict__ n1,
    u16* __restrict__ emb_bf, u16* __restrict__ sw1, u16* __restrict__ w3t,
    int* __restrict__ n2p, int* __restrict__ n1p, float* __restrict__ nw1)
{
    const int bx = blockIdx.x, t = threadIdx.x;
    if (bx < 2500) {                       // embedding -> bf16, 8 elems/thread
        int idx = bx * 256 + t;
        const float4* src = reinterpret_cast<const float4*>(emb) + (size_t)idx * 2;
        float4 a = src[0], c = src[1];
        u16 o[8] = {f2bf(a.x), f2bf(a.y), f2bf(a.z), f2bf(a.w),
                    f2bf(c.x), f2bf(c.y), f2bf(c.z), f2bf(c.w)};
        *reinterpret_cast<uint4*>(emb_bf + (size_t)idx * 8) = *reinterpret_cast<uint4*>(o);
    } else if (bx < 2756) {                // sessW1: block = (hop,b)
        int id = bx - 2500, hop = id >> 7, b = id & 127;
        const float* w1s = w1 + hop * 129 * 128;
        const float* se = session + b * 128;
        int n = t >> 1, kh = (t & 1) * 64;
        u16* dst = sw1 + (((size_t)(hop * 128 + b) * 128 + n) * 128) + kh;
        for (int kq = 0; kq < 64; kq += 8) {
            u16 o[8];
            #pragma unroll
            for (int e = 0; e < 8; ++e) { int k = kh + kq + e; o[e] = f2bf(w1s[k * 128 + n] * se[k]); }
            *reinterpret_cast<uint4*>(dst + kq) = *reinterpret_cast<uint4*>(o);
        }
    } else if (bx < 2788) {                // W3T [hop][n][k]
        int j = (bx - 2756) * 256 + t;     // < 8192
        int hop = j >> 12, r = j & 4095, n = r >> 5, k0 = (r & 31) * 8;
        const float* w3s = w3 + hop * 256 * 128;
        u16 o[8];
        #pragma unroll
        for (int e = 0; e < 8; ++e) o[e] = f2bf(w3s[(k0 + e) * 128 + n]);
        *reinterpret_cast<uint4*>(w3t + ((size_t)hop * 128 + n) * 256 + k0) = *reinterpret_cast<uint4*>(o);
    } else if (bx < 6388) {                // n2p (permuted byte-offsets) + nw1
        int idx = (bx - 2788) * 256 + t;
        if (idx < BATCH * 7200) {
            int b = idx / 7200, r = idx % 7200;
            int lblk = r / 96, q = r % 96;
            int i = q >> 4, c = q & 15;
            int gm = lblk * 96 + (c >> 2) * 24 + i * 4 + (c & 3);
            int node = n1[b * 600 + gm / SAMPLE];
            int s = gm % SAMPLE;
            n2p[idx] = adj_all[node * SAMPLE + s] << 8;
            nw1[b * 7200 + gm] = num_weight[node * SAMPLE + s];
        }
    } else {                               // n1p (mode0, permuted byte-offsets)
        int idx = (bx - 6388) * 256 + t;
        if (idx < BATCH * 672) {
            int b = idx / 672, r = idx % 672;
            int lblk = r / 96, q = r % 96;
            int i = q >> 4, c = q & 15;
            int gm = lblk * 96 + (c >> 2) * 24 + i * 4 + (c & 3);
            int jc = (gm < 600) ? gm : 0;
            n1p[idx] = n1[b * 600 + jc] << 8;
        }
    }
}

// ---------------------------------------------------------------------------
// Fused main kernel. 8 l-rows (96 samples) per block, 4 waves, 2 barriers.
// PATH 0, grid (83,128): bx==0 -> local_agg -> d_out; bx 1..7 -> mode0 -> out0;
//                        bx 8..82 -> mode1 -> out1.
// PATH 2, grid (7,128):  mode2 (self=out0, neigh=out1, hop1) += d_out.
//
// Register discipline (rounds 5/6 lesson): the unified VGPR file splits
// ~64 arch + ~64 accum at 4 waves/SIMD. Any per-lane f32 array that lives
// ACROSS the GEMM2 MFMA loop spills to scratch (640+ MB of traffic). So the
// softmax weights go to LDS (alphL) and are re-read as volatile scalars.
// ---------------------------------------------------------------------------
template <int PATH>
__global__ __launch_bounds__(256, 4) void main_kernel(
    const int* __restrict__ inputs, const int* __restrict__ adj,
    const u16* __restrict__ emb_bf, const float* __restrict__ a_local,
    const int* __restrict__ n1, const int* __restrict__ n2p,
    const int* __restrict__ n1p,
    const float* __restrict__ nw0, const float* __restrict__ nw1,
    const u16* __restrict__ sw1, const float* __restrict__ w1,
    const float* __restrict__ w2, const u16* __restrict__ w3t,
    const u16* __restrict__ in0, const u16* __restrict__ in1,
    u16* __restrict__ o0, u16* __restrict__ o1, float* __restrict__ outf)
{
    __shared__ __align__(16) char smem[30976];
    const int b = blockIdx.y;
    const int t = threadIdx.x;
    const int bx = blockIdx.x;

    if (PATH == 0 && bx == 0) {
        // ------------------- local aggregation (conflict-free layout) -----
        u16*   ht    = (u16*)smem;              // [128][52] bf16 = 13312 B
        float* alpha = (float*)(smem + 13312);  // [50][51] f32  = 10200 B
        u16*   alb   = (u16*)(smem + 23520);    // [4][128] bf16 = 1024 B

        for (int idx = t; idx < S * D; idx += 256) {
            int i = idx >> 7, d = idx & 127;
            ht[d * 52 + i] = emb_bf[(size_t)inputs[b * S + i] * D + d];
        }
        for (int idx = t; idx < 512; idx += 256) alb[idx] = f2bf(a_local[idx]);
        __syncthreads();

        for (int p = t; p < S * S; p += 256) {
            int i = p / S, j = p % S;
            int a = adj[b * S * S + p];
            float v = -9e15f;
            if (a >= 1 && a <= 4) {
                const u16* ak = alb + (a - 1) * D;
                float dot = 0.f;
                #pragma unroll 4
                for (int d = 0; d < D; ++d)
                    dot += bf2f(ht[d * 52 + i]) * bf2f(ht[d * 52 + j]) * bf2f(ak[d]);
                v = leakyf(dot);
            }
            alpha[i * 51 + j] = v;
        }
        __syncthreads();

        if (t < S) {
            float m = -INFINITY;
            for (int j = 0; j < S; ++j) m = fmaxf(m, alpha[t * 51 + j]);
            float ssum = 0.f;
            for (int j = 0; j < S; ++j) { float e = __expf(alpha[t * 51 + j] - m); alpha[t * 51 + j] = e; ssum += e; }
            float inv = 1.f / ssum;
            for (int j = 0; j < S; ++j) alpha[t * 51 + j] *= inv;
        }
        __syncthreads();

        for (int idx = t; idx < S * D; idx += 256) {
            int i = idx >> 7, d = idx & 127;
            float acc = 0.f;
            #pragma unroll 5
            for (int j = 0; j < S; ++j) acc += alpha[i * 51 + j] * bf2f(ht[d * 52 + j]);
            outf[(size_t)b * S * D + idx] = acc;
        }
        return;
    }

    // ------------------- global aggregation -------------------
    int mode, lblk, L, Lm, hop;
    const u16 *nsrc, *ssrc;
    const int* ptab; const float* nwTab;
    u16* outb;
    if (PATH == 2)    { mode = 2; lblk = bx;     L = 50;  Lm = 600;  hop = 1; nsrc = in1;    ssrc = in0;    ptab = nullptr;                   nwTab = nw0; outb = nullptr; }
    else if (bx >= 8) { mode = 1; lblk = bx - 8; L = 600; Lm = 7200; hop = 0; nsrc = emb_bf; ssrc = emb_bf; ptab = n2p + (b * 75 + lblk) * 96; nwTab = nw1; outb = o1; }
    else              { mode = 0; lblk = bx - 1; L = 50;  Lm = 600;  hop = 0; nsrc = emb_bf; ssrc = emb_bf; ptab = n1p + (b * 7 + lblk) * 96;  nwTab = nw0; outb = o0; }
    const int l0 = lblk * 8;

    u16*   nvL     = (u16*)smem;              // 1536 slots * 16B = 24576
    u16*   selfL   = (u16*)(smem + 24576);    // 256 slots * 16B = 4096
    float* score_w = (float*)(smem + 28672);  // [96][4] = 1536
    float* nwgtL   = (float*)(smem + 30208);  // 96 floats = 384
    float* alphL   = (float*)(smem + 30592);  // 96 floats = 384

    const u16*   sw1b   = sw1 + (size_t)(hop * 128 + b) * 16384;
    const float* w1last = w1 + hop * 129 * 128 + 128 * 128;
    const float* w2h    = w2 + hop * 128;
    const u16*   w3th   = w3t + hop * 32768;

    const int lane = t & 63, wv = t >> 6, cn = lane & 15, cg = lane >> 4;
    const int nc0 = (2 * wv) * 16 + cn, nc1 = (2 * wv + 1) * 16 + cn;
    const int c = t & 15;        // row selector within 16-row group
    const int chunk = t >> 4;    // 16B chunk 0..15 of a 256B row

    // ---- stage neighbor rows (fragment order, conflict-free) ----
    #pragma unroll
    for (int i = 0; i < 6; ++i) {
        int off;
        if (PATH == 2) {
            int gm = l0 * 12 + (c >> 2) * 24 + i * 4 + (c & 3);
            if (gm > 599) gm = 599;
            off = (b * 600 + gm) << 8;
        } else {
            off = ptab[i * 16 + c];   // 64B broadcast load
        }
        uint4 v = *reinterpret_cast<const uint4*>((const char*)nsrc + (unsigned)off + chunk * 16);
        *reinterpret_cast<uint4*>(nvL + (i * 256 + t) * 8) = v;
    }
    // ---- stage self rows: A row i2 holds l = 2*(i2>>2) + ((i2>>1)&1) ----
    {
        int l = 2 * (c >> 2) + ((c >> 1) & 1);
        int lg = l0 + l; if (lg >= L) lg = 0;
        int srow;
        if (PATH == 2)      srow = b * 50 + lg;
        else if (mode == 1) srow = n1[b * 600 + lg];
        else                srow = inputs[b * S + lg];
        uint4 v = *reinterpret_cast<const uint4*>(ssrc + (size_t)srow * 128 + chunk * 8);
        *reinterpret_cast<uint4*>(selfL + t * 8) = v;
    }
    if (t < 96) {
        int gm = l0 * 12 + t;
        nwgtL[t] = (gm < Lm) ? nwTab[b * Lm + gm] : 0.f;
    }
    __syncthreads();

    // ---- GEMM1: z[96,128] = nv @ sessW1 ----
    f32x4 acc[6][2];
    #pragma unroll
    for (int mt = 0; mt < 6; ++mt) {
        acc[mt][0] = (f32x4){0.f, 0.f, 0.f, 0.f};
        acc[mt][1] = (f32x4){0.f, 0.f, 0.f, 0.f};
    }
    #pragma unroll
    for (int kk = 0; kk < 4; ++kk) {
        int kb = kk * 32 + cg * 8;
        short8v b0 = *reinterpret_cast<const short8v*>(sw1b + nc0 * 128 + kb);
        short8v b1 = *reinterpret_cast<const short8v*>(sw1b + nc1 * 128 + kb);
        #pragma unroll
        for (int mt = 0; mt < 6; ++mt) {
            short8v a = *reinterpret_cast<const short8v*>(nvL + ((mt * 4 + kk) * 64 + lane) * 8);
            acc[mt][0] = __builtin_amdgcn_mfma_f32_16x16x32_bf16(a, b0, acc[mt][0], 0, 0, 0);
            acc[mt][1] = __builtin_amdgcn_mfma_f32_16x16x32_bf16(a, b1, acc[mt][1], 0, 0, 0);
        }
    }
    // ---- score epilogue: K=129 rank-1 + leaky + @W2, reduce over 16 lanes ----
    {
        float w2v0 = w2h[nc0], w2v1 = w2h[nc1];
        float w1l0 = w1last[nc0], w1l1 = w1last[nc1];
        #pragma unroll
        for (int mt = 0; mt < 6; ++mt) {
            #pragma unroll
            for (int r = 0; r < 4; ++r) {
                int m = cg * 24 + mt * 4 + r;
                float nw = nwgtL[m];
                float v = leakyf(acc[mt][0][r] + nw * w1l0) * w2v0 +
                          leakyf(acc[mt][1][r] + nw * w1l1) * w2v1;
                v += __shfl_xor(v, 1); v += __shfl_xor(v, 2);
                v += __shfl_xor(v, 4); v += __shfl_xor(v, 8);
                if (cn == 0) score_w[m * 4 + wv] = v;
            }
        }
    }
    __syncthreads();

    // ---- per-lane redundant softmax over 12 samples for l=2cg, 2cg+1;
    //      results parked in LDS so no f32[24] survives into GEMM2 ----
    {
        float alph[24];
        const f32x4* sw4 = reinterpret_cast<const f32x4*>(score_w);
        float mx0 = -1e30f, mx1 = -1e30f;
        #pragma unroll
        for (int q = 0; q < 24; ++q) {
            f32x4 s4 = sw4[cg * 24 + q];
            float s = (s4[0] + s4[1]) + (s4[2] + s4[3]);
            alph[q] = s;
            if (q < 12) mx0 = fmaxf(mx0, s); else mx1 = fmaxf(mx1, s);
        }
        float sm0 = 0.f, sm1 = 0.f;
        #pragma unroll
        for (int q = 0; q < 12; ++q) { alph[q] = __expf(alph[q] - mx0); sm0 += alph[q]; }
        #pragma unroll
        for (int q = 12; q < 24; ++q) { alph[q] = __expf(alph[q] - mx1); sm1 += alph[q]; }
        float i0 = 1.f / sm0, i1 = 1.f / sm1;
        // every wave writes the (bit-identical) values for all its cg groups;
        // readers are in the same wave, so ds-op ordering suffices (no barrier)
        if (cn == 0) {
            #pragma unroll
            for (int q = 0; q < 12; ++q)  alphL[cg * 24 + q] = alph[q] * i0;
            #pragma unroll
            for (int q = 12; q < 24; ++q) alphL[cg * 24 + q] = alph[q] * i1;
        }
    }

    // ---- GEMM2 per output col: Y = nv @ W3b, Ys = self @ W3a; combine ----
    // volatile LDS reads so the compiler can't hoist 24 alphas back into regs
    volatile const float* alphV = alphL;
    #pragma unroll
    for (int j = 0; j < 2; ++j) {
        int nc = (2 * wv + j) * 16 + cn;
        f32x4 Y[6]; f32x4 Ys = (f32x4){0.f, 0.f, 0.f, 0.f};
        #pragma unroll
        for (int mt = 0; mt < 6; ++mt) Y[mt] = (f32x4){0.f, 0.f, 0.f, 0.f};
        #pragma unroll
        for (int kk = 0; kk < 4; ++kk) {
            int kb = kk * 32 + cg * 8;
            short8v bw = *reinterpret_cast<const short8v*>(w3th + nc * 256 + 128 + kb);
            short8v bs = *reinterpret_cast<const short8v*>(w3th + nc * 256 + kb);
            short8v aS = *reinterpret_cast<const short8v*>(selfL + (kk * 64 + lane) * 8);
            Ys = __builtin_amdgcn_mfma_f32_16x16x32_bf16(aS, bs, Ys, 0, 0, 0);
            #pragma unroll
            for (int mt = 0; mt < 6; ++mt) {
                short8v a = *reinterpret_cast<const short8v*>(nvL + ((mt * 4 + kk) * 64 + lane) * 8);
                Y[mt] = __builtin_amdgcn_mfma_f32_16x16x32_bf16(a, bw, Y[mt], 0, 0, 0);
            }
        }
        float P0 = 0.f, P1 = 0.f;
        #pragma unroll
        for (int q = 0; q < 12; ++q) P0 += alphV[cg * 24 + q] * Y[q >> 2][q & 3];
        #pragma unroll
        for (int q = 12; q < 24; ++q) P1 += alphV[cg * 24 + q] * Y[q >> 2][q & 3];
        float v0 = fmaxf(P0 + Ys[0], 0.f);   // l = 2cg
        float v1 = fmaxf(P1 + Ys[2], 0.f);   // l = 2cg+1
        int lg0 = l0 + cg * 2, lg1 = lg0 + 1;
        if (PATH == 2) {
            if (lg0 < L) { float* p = outf + ((size_t)b * 50 + lg0) * 128 + nc; *p += v0; }
            if (lg1 < L) { float* p = outf + ((size_t)b * 50 + lg1) * 128 + nc; *p += v1; }
        } else {
            if (lg0 < L) outb[((size_t)b * L + lg0) * 128 + nc] = f2bf(v0);
            if (lg1 < L) outb[((size_t)b * L + lg1) * 128 + nc] = f2bf(v1);
        }
    }
}

// ---------------------------------------------------------------------------
extern "C" void kernel_launch(void* const* d_in, const int* in_sizes, int n_in,
                              void* d_out, int out_size, void* d_ws, size_t ws_size,
                              hipStream_t stream)
{
    const int*   inputs     = (const int*)d_in[0];
    const int*   adj        = (const int*)d_in[1];
    const int*   mask_item  = (const int*)d_in[2];
    const int*   item       = (const int*)d_in[3];
    const int*   adj_all    = (const int*)d_in[4];
    const float* num_weight = (const float*)d_in[5];
    const float* embedding  = (const float*)d_in[6];
    const float* a_local    = (const float*)d_in[7];
    const float* agg_w1     = (const float*)d_in[8];
    const float* agg_w2     = (const float*)d_in[9];
    const float* agg_w3     = (const float*)d_in[10];
    float* out = (float*)d_out;

    // workspace layout (16B aligned)
    char* w = (char*)d_ws;
    float* ws_session = (float*)(w);               //     65,536 B
    int*   ws_n1      = (int*)(w + 65536);         //    307,200 B
    float* ws_nw0     = (float*)(w + 372736);      //    307,200 B
    float* ws_nw1     = (float*)(w + 679936);      //  3,686,400 B
    int*   ws_n2p     = (int*)(w + 4366336);       //  3,686,400 B
    int*   ws_n1p     = (int*)(w + 8052736);       //    344,064 B
    u16*   ws_emb     = (u16*)(w + 8396800);       // 10,240,000 B
    u16*   ws_sw1     = (u16*)(w + 18636800);      //  8,388,608 B
    u16*   ws_w3t     = (u16*)(w + 27025408);      //    131,072 B
    u16*   ws_out0    = (u16*)(w + 27156480);      //  1,638,400 B
    u16*   ws_out1    = (u16*)(w + 28794880);      // 19,660,800 B (end ~46.2 MB)

    setup1_kernel<<<dim3(BATCH + 300), 256, 0, stream>>>(
        item, mask_item, inputs, adj_all, num_weight, embedding,
        ws_session, ws_n1, ws_nw0);
    prep2_kernel<<<dim3(6724), 256, 0, stream>>>(
        embedding, agg_w1, agg_w3, ws_session, adj_all, num_weight, ws_n1,
        ws_emb, ws_sw1, ws_w3t, ws_n2p, ws_n1p, ws_nw1);

    // fused: local (bx=0) + mode0 (bx 1..7) + mode1 (bx 8..82) per batch
    main_kernel<0><<<dim3(83, BATCH), 256, 0, stream>>>(
        inputs, adj, ws_emb, a_local, ws_n1, ws_n2p, ws_n1p, ws_nw0, ws_nw1,
        ws_sw1, agg_w1, agg_w2, ws_w3t,
        nullptr, nullptr, ws_out0, ws_out1, out);

    // mode2: hop-1 weights, self=out0, neigh=out1, += h_local in d_out
    main_kernel<2><<<dim3(7, BATCH), 256, 0, stream>>>(
        inputs, adj, ws_emb, a_local, ws_n1, ws_n2p, ws_n1p, ws_nw0, ws_nw1,
        ws_sw1, agg_w1, agg_w2, ws_w3t,
        ws_out0, ws_out1, nullptr, nullptr, out);
}